// Round 1
// baseline (26333.890 us; speedup 1.0000x reference)
//
#include <hip/hip_runtime.h>

// Problem constants
#define B_ 64
#define S_ 64
#define T_ 64
#define V_ 32000
#define D_ 512
#define H_ 1024
#define L_ 256

// ---------------------------------------------------------------------------
// LDS staging: 64 rows x 256 cols (float) of A into swizzled float4 chunks.
// Chunk index: m*64 + (kf ^ (m&7)) -- spreads the stride-1024B rows across
// all 32 banks so ds_read_b128 at lane==m is conflict-free.
// ---------------------------------------------------------------------------
__device__ __forceinline__ void stage_rows(float4* a_lds, const float* __restrict__ A,
                                           int rowStride, int k0, int tid) {
  const int kf = tid & 63;
  const int msub = tid >> 6;
#pragma unroll
  for (int p = 0; p < 16; ++p) {
    const int m = p * 4 + msub;
    float4 v = *reinterpret_cast<const float4*>(A + (long long)m * rowStride + k0 + kf * 4);
    a_lds[m * 64 + (kf ^ (m & 7))] = v;
  }
}

__device__ __forceinline__ void stage_rows_gather(float4* a_lds, const float* __restrict__ E,
                                                  const int* __restrict__ tokp, int tokStride,
                                                  int k0, int tid) {
  const int kf = tid & 63;
  const int msub = tid >> 6;
#pragma unroll
  for (int p = 0; p < 16; ++p) {
    const int m = p * 4 + msub;
    const long long row = (long long)tokp[m * tokStride] * D_;
    float4 v = *reinterpret_cast<const float4*>(E + row + k0 + kf * 4);
    a_lds[m * 64 + (kf ^ (m & 7))] = v;
  }
}

// ---------------------------------------------------------------------------
// Fused GRU step (PyTorch GRUCell math), one kernel per timestep.
// grid=256, block=256. wave w handles gate-column j = blockIdx*4 + w for all
// 64 batch rows (lane == b). 4 accumulators per thread: r, z, i_n, h_n.
// Gates applied in the epilogue -> h_out written directly.
// ---------------------------------------------------------------------------
template <bool USE_X>
__global__ __launch_bounds__(256) void k_gru_step(
    const float* __restrict__ E, const int* __restrict__ tokp, int tokStride,
    const float* __restrict__ W_ih, const float* __restrict__ W_hh,
    const float* __restrict__ b_ih, const float* __restrict__ b_hh,
    const float* __restrict__ h_in, float* __restrict__ h_out)
{
  __shared__ float4 a_lds[64 * 64];  // 64 KiB
  const int tid = threadIdx.x;
  const int lane = tid & 63;
  const int wv = __builtin_amdgcn_readfirstlane(tid >> 6);
  const int j = blockIdx.x * 4 + wv;

  float accR = 0.f, accZ = 0.f, accIN = 0.f, accHN = 0.f;

  if constexpr (USE_X) {
    const float* wr = W_ih + (long long)j * D_;
    const float* wz = W_ih + (long long)(j + H_) * D_;
    const float* wn = W_ih + (long long)(j + 2 * H_) * D_;
    for (int k0 = 0; k0 < D_; k0 += 256) {
      __syncthreads();
      stage_rows_gather(a_lds, E, tokp, tokStride, k0, tid);
      __syncthreads();
#pragma unroll 8
      for (int kf = 0; kf < 64; ++kf) {
        float4 a = a_lds[lane * 64 + (kf ^ (lane & 7))];
        float4 w0 = *reinterpret_cast<const float4*>(wr + k0 + kf * 4);
        float4 w1 = *reinterpret_cast<const float4*>(wz + k0 + kf * 4);
        float4 w2 = *reinterpret_cast<const float4*>(wn + k0 + kf * 4);
        accR = fmaf(w0.x, a.x, accR); accR = fmaf(w0.y, a.y, accR);
        accR = fmaf(w0.z, a.z, accR); accR = fmaf(w0.w, a.w, accR);
        accZ = fmaf(w1.x, a.x, accZ); accZ = fmaf(w1.y, a.y, accZ);
        accZ = fmaf(w1.z, a.z, accZ); accZ = fmaf(w1.w, a.w, accZ);
        accIN = fmaf(w2.x, a.x, accIN); accIN = fmaf(w2.y, a.y, accIN);
        accIN = fmaf(w2.z, a.z, accIN); accIN = fmaf(w2.w, a.w, accIN);
      }
    }
  }

  {
    const float* wr = W_hh + (long long)j * H_;
    const float* wz = W_hh + (long long)(j + H_) * H_;
    const float* wn = W_hh + (long long)(j + 2 * H_) * H_;
    for (int k0 = 0; k0 < H_; k0 += 256) {
      __syncthreads();
      stage_rows(a_lds, h_in, H_, k0, tid);
      __syncthreads();
#pragma unroll 8
      for (int kf = 0; kf < 64; ++kf) {
        float4 a = a_lds[lane * 64 + (kf ^ (lane & 7))];
        float4 w0 = *reinterpret_cast<const float4*>(wr + k0 + kf * 4);
        float4 w1 = *reinterpret_cast<const float4*>(wz + k0 + kf * 4);
        float4 w2 = *reinterpret_cast<const float4*>(wn + k0 + kf * 4);
        accR = fmaf(w0.x, a.x, accR); accR = fmaf(w0.y, a.y, accR);
        accR = fmaf(w0.z, a.z, accR); accR = fmaf(w0.w, a.w, accR);
        accZ = fmaf(w1.x, a.x, accZ); accZ = fmaf(w1.y, a.y, accZ);
        accZ = fmaf(w1.z, a.z, accZ); accZ = fmaf(w1.w, a.w, accZ);
        accHN = fmaf(w2.x, a.x, accHN); accHN = fmaf(w2.y, a.y, accHN);
        accHN = fmaf(w2.z, a.z, accHN); accHN = fmaf(w2.w, a.w, accHN);
      }
    }
  }

  // Epilogue: gates
  const float gr = accR + b_ih[j] + b_hh[j];
  const float gz = accZ + b_ih[H_ + j] + b_hh[H_ + j];
  const float gin = accIN + b_ih[2 * H_ + j];
  const float ghn = accHN + b_hh[2 * H_ + j];
  const float r = 1.f / (1.f + expf(-gr));
  const float z = 1.f / (1.f + expf(-gz));
  const float n = tanhf(fmaf(r, ghn, gin));
  const long long off = (long long)lane * H_ + j;
  const float hp = h_in[off];
  h_out[off] = (1.f - z) * n + z * hp;
}

// ---------------------------------------------------------------------------
// Logits GEMM: out[b, t, n] = h[b,:] . W_out[n,:] + b_out[n]
// grid=500, block=256. Block covers 64 n-cols; wave covers 16; lane == b.
// 16 fp32 accumulators/thread, A staged in swizzled LDS, W via uniform loads.
// ---------------------------------------------------------------------------
__global__ __launch_bounds__(256) void k_logits(
    const float* __restrict__ h, const float* __restrict__ W_out,
    const float* __restrict__ b_out, float* __restrict__ out, int t)
{
  __shared__ float4 a_lds[64 * 64];
  const int tid = threadIdx.x;
  const int lane = tid & 63;
  const int wv = __builtin_amdgcn_readfirstlane(tid >> 6);
  const int n0 = blockIdx.x * 64 + wv * 16;

  float acc[16];
#pragma unroll
  for (int r = 0; r < 16; ++r) acc[r] = 0.f;

  for (int k0 = 0; k0 < H_; k0 += 256) {
    __syncthreads();
    stage_rows(a_lds, h, H_, k0, tid);
    __syncthreads();
#pragma unroll 4
    for (int kf = 0; kf < 64; ++kf) {
      float4 a = a_lds[lane * 64 + (kf ^ (lane & 7))];
#pragma unroll
      for (int r = 0; r < 16; ++r) {
        float4 w = *reinterpret_cast<const float4*>(W_out + (long long)(n0 + r) * H_ + k0 + kf * 4);
        acc[r] = fmaf(w.x, a.x, acc[r]);
        acc[r] = fmaf(w.y, a.y, acc[r]);
        acc[r] = fmaf(w.z, a.z, acc[r]);
        acc[r] = fmaf(w.w, a.w, acc[r]);
      }
    }
  }

  float* orow = out + (long long)lane * (T_ * (long long)V_) + (long long)t * V_ + n0;
#pragma unroll
  for (int g = 0; g < 4; ++g) {
    float4 o;
    o.x = acc[g * 4 + 0] + b_out[n0 + g * 4 + 0];
    o.y = acc[g * 4 + 1] + b_out[n0 + g * 4 + 1];
    o.z = acc[g * 4 + 2] + b_out[n0 + g * 4 + 2];
    o.w = acc[g * 4 + 3] + b_out[n0 + g * 4 + 3];
    *reinterpret_cast<float4*>(orow + g * 4) = o;
  }
}

// ---------------------------------------------------------------------------
// Row argmax over V with first-occurrence tie-break (matches jnp.argmax).
// grid=64 (one block per b), block=256.
// ---------------------------------------------------------------------------
__global__ __launch_bounds__(256) void k_argmax(const float* __restrict__ out, int t,
                                                int* __restrict__ tok)
{
  const int b = blockIdx.x;
  const int tid = threadIdx.x;
  const float4* row = reinterpret_cast<const float4*>(
      out + (long long)b * (T_ * (long long)V_) + (long long)t * V_);
  float best = -3.4e38f;
  int bi = 0;
  for (int v4 = tid; v4 < V_ / 4; v4 += 256) {
    float4 x = row[v4];
    const int base = v4 * 4;
    if (x.x > best) { best = x.x; bi = base; }
    if (x.y > best) { best = x.y; bi = base + 1; }
    if (x.z > best) { best = x.z; bi = base + 2; }
    if (x.w > best) { best = x.w; bi = base + 3; }
  }
  __shared__ float sv[256];
  __shared__ int si[256];
  sv[tid] = best; si[tid] = bi;
  __syncthreads();
  for (int s = 128; s > 0; s >>= 1) {
    if (tid < s) {
      const float ov = sv[tid + s]; const int oi = si[tid + s];
      if (ov > sv[tid] || (ov == sv[tid] && oi < si[tid])) { sv[tid] = ov; si[tid] = oi; }
    }
    __syncthreads();
  }
  if (tid == 0) tok[b] = si[0];
}

// ---------------------------------------------------------------------------
// mu / logvar / z: grid=64, block=256, wave covers one latent col l, lane==b.
// ---------------------------------------------------------------------------
__global__ __launch_bounds__(256) void k_mu_lv_z(
    const float* __restrict__ h, const float* __restrict__ W_mu, const float* __restrict__ b_mu,
    const float* __restrict__ W_lv, const float* __restrict__ b_lv,
    const float* __restrict__ eps, float* __restrict__ out_mu, float* __restrict__ out_lv,
    float* __restrict__ z)
{
  __shared__ float4 a_lds[64 * 64];
  const int tid = threadIdx.x;
  const int lane = tid & 63;
  const int wv = __builtin_amdgcn_readfirstlane(tid >> 6);
  const int l = blockIdx.x * 4 + wv;
  float am = 0.f, av = 0.f;
  const float* wm = W_mu + (long long)l * H_;
  const float* wl = W_lv + (long long)l * H_;
  for (int k0 = 0; k0 < H_; k0 += 256) {
    __syncthreads();
    stage_rows(a_lds, h, H_, k0, tid);
    __syncthreads();
#pragma unroll 8
    for (int kf = 0; kf < 64; ++kf) {
      float4 a = a_lds[lane * 64 + (kf ^ (lane & 7))];
      float4 w0 = *reinterpret_cast<const float4*>(wm + k0 + kf * 4);
      float4 w1 = *reinterpret_cast<const float4*>(wl + k0 + kf * 4);
      am = fmaf(w0.x, a.x, am); am = fmaf(w0.y, a.y, am);
      am = fmaf(w0.z, a.z, am); am = fmaf(w0.w, a.w, am);
      av = fmaf(w1.x, a.x, av); av = fmaf(w1.y, a.y, av);
      av = fmaf(w1.z, a.z, av); av = fmaf(w1.w, a.w, av);
    }
  }
  const float mu = am + b_mu[l];
  const float lv = av + b_lv[l];
  const int off = lane * L_ + l;
  out_mu[off] = mu;
  out_lv[off] = lv;
  z[off] = fmaf(eps[off], expf(0.5f * lv), mu);
}

// ---------------------------------------------------------------------------
// h_dec0 = z @ W_proj.T + b_proj. grid=256, block=256, K=256 (one chunk).
// ---------------------------------------------------------------------------
__global__ __launch_bounds__(256) void k_proj(
    const float* __restrict__ z, const float* __restrict__ W_proj,
    const float* __restrict__ b_proj, float* __restrict__ h0)
{
  __shared__ float4 a_lds[64 * 64];
  const int tid = threadIdx.x;
  const int lane = tid & 63;
  const int wv = __builtin_amdgcn_readfirstlane(tid >> 6);
  const int j = blockIdx.x * 4 + wv;
  stage_rows(a_lds, z, L_, 0, tid);
  __syncthreads();
  float acc = 0.f;
  const float* wr = W_proj + (long long)j * L_;
#pragma unroll 8
  for (int kf = 0; kf < 64; ++kf) {
    float4 a = a_lds[lane * 64 + (kf ^ (lane & 7))];
    float4 w = *reinterpret_cast<const float4*>(wr + kf * 4);
    acc = fmaf(w.x, a.x, acc); acc = fmaf(w.y, a.y, acc);
    acc = fmaf(w.z, a.z, acc); acc = fmaf(w.w, a.w, acc);
  }
  h0[(long long)lane * H_ + j] = acc + b_proj[j];
}

// ---------------------------------------------------------------------------
extern "C" void kernel_launch(void* const* d_in, const int* in_sizes, int n_in,
                              void* d_out, int out_size, void* d_ws, size_t ws_size,
                              hipStream_t stream) {
  (void)in_sizes; (void)n_in; (void)out_size; (void)ws_size;
  const int*   x        = (const int*)d_in[0];
  const float* eps      = (const float*)d_in[1];
  const float* E        = (const float*)d_in[2];
  const float* W_ih_enc = (const float*)d_in[3];
  const float* W_hh_enc = (const float*)d_in[4];
  const float* b_ih_enc = (const float*)d_in[5];
  const float* b_hh_enc = (const float*)d_in[6];
  const float* W_mu     = (const float*)d_in[7];
  const float* b_mu     = (const float*)d_in[8];
  const float* W_lv     = (const float*)d_in[9];
  const float* b_lv     = (const float*)d_in[10];
  const float* W_proj   = (const float*)d_in[11];
  const float* b_proj   = (const float*)d_in[12];
  const float* W_ih_dec = (const float*)d_in[13];
  const float* W_hh_dec = (const float*)d_in[14];
  const float* b_ih_dec = (const float*)d_in[15];
  const float* b_hh_dec = (const float*)d_in[16];
  const float* W_out    = (const float*)d_in[17];
  const float* b_out    = (const float*)d_in[18];

  float* out = (float*)d_out;
  const long long OFF_MU = (long long)B_ * T_ * V_;
  const long long OFF_LV = OFF_MU + (long long)B_ * L_;

  float* ws = (float*)d_ws;
  float* hA = ws;                 // [64,1024]
  float* hB = ws + 65536;         // [64,1024]
  float* dA = ws + 131072;        // [64,1024]
  float* dB = ws + 196608;        // [64,1024]
  float* zb = ws + 262144;        // [64,256]
  int*   tok = (int*)(ws + 278528); // [64]

  hipMemsetAsync(hA, 0, (size_t)B_ * H_ * sizeof(float), stream);

  // ---- encoder ----
  for (int t = 0; t < S_; ++t) {
    const float* hin = (t & 1) ? hB : hA;
    float* hout = (t & 1) ? hA : hB;
    k_gru_step<true><<<256, 256, 0, stream>>>(E, x + t, S_, W_ih_enc, W_hh_enc,
                                              b_ih_enc, b_hh_enc, hin, hout);
  }
  // h_last in hA (S_=64 even)

  // ---- latent ----
  k_mu_lv_z<<<64, 256, 0, stream>>>(hA, W_mu, b_mu, W_lv, b_lv, eps,
                                    out + OFF_MU, out + OFF_LV, zb);
  k_proj<<<256, 256, 0, stream>>>(zb, W_proj, b_proj, dA);

  // ---- decoder ----
  for (int t = 0; t < T_; ++t) {
    const float* hin = (t & 1) ? dB : dA;
    float* hout = (t & 1) ? dA : dB;
    if (t == 0) {
      k_gru_step<false><<<256, 256, 0, stream>>>(nullptr, nullptr, 0, W_ih_dec, W_hh_dec,
                                                 b_ih_dec, b_hh_dec, hin, hout);
    } else {
      k_gru_step<true><<<256, 256, 0, stream>>>(E, tok, 1, W_ih_dec, W_hh_dec,
                                                b_ih_dec, b_hh_dec, hin, hout);
    }
    k_logits<<<500, 256, 0, stream>>>(hout, W_out, b_out, out, t);
    if (t < T_ - 1) k_argmax<<<64, 256, 0, stream>>>(out, t, tok);
  }
}

// Round 2
// 10538.752 us; speedup vs baseline: 2.4988x; 2.4988x over previous
//
#include <hip/hip_runtime.h>

// Problem constants
#define B_ 64
#define S_ 64
#define T_ 64
#define V_ 32000
#define D_ 512
#define H_ 1024
#define L_ 256

// ---------------------------------------------------------------------------
// OLD-style LDS staging helper (256-thread blocks): 64 rows x 256 floats,
// swizzled float4 chunks. Used by the small one-shot kernels (mu/lv/z, proj).
// ---------------------------------------------------------------------------
__device__ __forceinline__ void stage_rows256(float4* a_lds, const float* __restrict__ A,
                                              int rowStride, int k0, int tid) {
  const int kf = tid & 63;
  const int msub = tid >> 6;
#pragma unroll
  for (int p = 0; p < 16; ++p) {
    const int m = p * 4 + msub;
    float4 v = *reinterpret_cast<const float4*>(A + (long long)m * rowStride + k0 + kf * 4);
    a_lds[m * 64 + (kf ^ (m & 7))] = v;
  }
}

// ---------------------------------------------------------------------------
// Encoder input-gates GEMM (hoisted out of the sequential loop):
// Gi[s][n][b] = sum_d E[x[b][s]][d] * W_ih_enc[n][d] + b_ih[n],  n in [0,3H)
// grid = 64 s * 48 ntiles = 3072 blocks, 256 threads. K=512, 4 chunks of 128.
// A (gathered embeddings) and W both staged in swizzled LDS.
// ---------------------------------------------------------------------------
__global__ __launch_bounds__(256) void k_gates_enc(
    const int* __restrict__ x, const float* __restrict__ E,
    const float* __restrict__ W_ih, const float* __restrict__ b_ih,
    float* __restrict__ Gi)
{
  __shared__ float4 a_lds[64 * 32];  // 32 KiB
  __shared__ float4 w_lds[64 * 32];  // 32 KiB
  const int tid = threadIdx.x;
  const int lane = tid & 63;
  const int wv = __builtin_amdgcn_readfirstlane(tid >> 6);
  const int s = blockIdx.x / 48;
  const int bn = (blockIdx.x % 48) * 64;

  float acc[16];
#pragma unroll
  for (int r = 0; r < 16; ++r) acc[r] = 0.f;

  const int akc = tid & 31;   // A: float4 col 0..31
  const int amsub = tid >> 5; // A: 0..7
  const int wrow = tid >> 2;  // W: row 0..63
  const int wfb = tid & 3;    // W: col phase

  for (int c = 0; c < 4; ++c) {
    __syncthreads();
#pragma unroll
    for (int p = 0; p < 8; ++p) {
      const int m = p * 8 + amsub;
      const long long tok = x[m * S_ + s];
      float4 v = *reinterpret_cast<const float4*>(E + tok * D_ + c * 128 + akc * 4);
      a_lds[m * 32 + (akc ^ (m & 7))] = v;
    }
#pragma unroll
    for (int i = 0; i < 8; ++i) {
      const int f = wfb + i * 4;
      float4 v = *reinterpret_cast<const float4*>(W_ih + (long long)(bn + wrow) * D_ + c * 128 + f * 4);
      w_lds[wrow * 32 + (f ^ (wrow & 7))] = v;
    }
    __syncthreads();
    for (int kc = 0; kc < 32; ++kc) {
      float4 a = a_lds[lane * 32 + (kc ^ (lane & 7))];
#pragma unroll
      for (int r = 0; r < 16; ++r) {
        const int row = wv * 16 + r;
        float4 w = w_lds[row * 32 + (kc ^ (row & 7))];
        acc[r] = fmaf(w.x, a.x, acc[r]); acc[r] = fmaf(w.y, a.y, acc[r]);
        acc[r] = fmaf(w.z, a.z, acc[r]); acc[r] = fmaf(w.w, a.w, acc[r]);
      }
    }
  }
  const int n0 = bn + wv * 16;
#pragma unroll
  for (int r = 0; r < 16; ++r) {
    const int n = n0 + r;
    Gi[((long long)s * (3 * H_) + n) * 64 + lane] = acc[r] + b_ih[n];  // coalesced in lane
  }
}

// ---------------------------------------------------------------------------
// GRU step, 16-wave version. grid=256 blocks x 1024 threads.
// Block owns 4 gate-columns j; wave wv: jj = wv&3, kslice ks = wv>>2.
// Each wave accumulates its 16-kf window per 256-col chunk; LDS reduce; ks==0
// waves apply gates and write h_out.
// XMODE: 0 = no x-part, 1 = tokens from int array (enc fallback, stride S_),
//        2 = tokens decoded from argmax keys (decoder).
// GI: add precomputed input gates Gi[n][b] (b_ih already folded in).
// ---------------------------------------------------------------------------
template <int XMODE, bool GI>
__global__ __launch_bounds__(1024) void k_gru16(
    const float* __restrict__ E, const int* __restrict__ toki,
    const unsigned long long* __restrict__ keys, const float* __restrict__ Gi,
    const float* __restrict__ W_ih, const float* __restrict__ W_hh,
    const float* __restrict__ b_ih, const float* __restrict__ b_hh,
    const float* __restrict__ h_in, float* __restrict__ h_out)
{
  __shared__ float4 a_lds[64 * 64];   // 64 KiB staging
  __shared__ float red[3 * 4 * 4 * 64]; // 12 KiB cross-wave reduction
  const int tid = threadIdx.x;
  const int lane = tid & 63;
  const int wv = __builtin_amdgcn_readfirstlane(tid >> 6);
  const int jj = wv & 3;
  const int ks = wv >> 2;
  const int j = blockIdx.x * 4 + jj;

  const int kf16 = tid & 63;
  const int msub = tid >> 6;  // 0..15

  float accR = 0.f, accZ = 0.f, accIN = 0.f, accHN = 0.f;

  // ---- hidden part: K = 1024, 4 chunks of 256 ----
  {
    const float* wr = W_hh + (long long)j * H_;
    const float* wz = W_hh + (long long)(j + H_) * H_;
    const float* wn = W_hh + (long long)(j + 2 * H_) * H_;
    for (int c = 0; c < 4; ++c) {
      __syncthreads();
#pragma unroll
      for (int p = 0; p < 4; ++p) {
        const int m = p * 16 + msub;
        float4 v = *reinterpret_cast<const float4*>(h_in + (long long)m * H_ + c * 256 + kf16 * 4);
        a_lds[m * 64 + (kf16 ^ (m & 7))] = v;
      }
      __syncthreads();
#pragma unroll 4
      for (int q = 0; q < 16; ++q) {
        const int kf = ks * 16 + q;
        float4 a = a_lds[lane * 64 + (kf ^ (lane & 7))];
        float4 w0 = *reinterpret_cast<const float4*>(wr + c * 256 + kf * 4);
        float4 w1 = *reinterpret_cast<const float4*>(wz + c * 256 + kf * 4);
        float4 w2 = *reinterpret_cast<const float4*>(wn + c * 256 + kf * 4);
        accR = fmaf(w0.x, a.x, accR); accR = fmaf(w0.y, a.y, accR);
        accR = fmaf(w0.z, a.z, accR); accR = fmaf(w0.w, a.w, accR);
        accZ = fmaf(w1.x, a.x, accZ); accZ = fmaf(w1.y, a.y, accZ);
        accZ = fmaf(w1.z, a.z, accZ); accZ = fmaf(w1.w, a.w, accZ);
        accHN = fmaf(w2.x, a.x, accHN); accHN = fmaf(w2.y, a.y, accHN);
        accHN = fmaf(w2.z, a.z, accHN); accHN = fmaf(w2.w, a.w, accHN);
      }
    }
  }

  // ---- input part: K = 512, 2 chunks of 256 (gathered embeddings) ----
  if constexpr (XMODE != 0) {
    const float* wr = W_ih + (long long)j * D_;
    const float* wz = W_ih + (long long)(j + H_) * D_;
    const float* wn = W_ih + (long long)(j + 2 * H_) * D_;
    for (int c = 0; c < 2; ++c) {
      __syncthreads();
#pragma unroll
      for (int p = 0; p < 4; ++p) {
        const int m = p * 16 + msub;
        long long tok;
        if constexpr (XMODE == 1) tok = toki[m * S_];
        else tok = (long long)(0xFFFFFFFFu - (unsigned)(keys[m] & 0xFFFFFFFFull));
        float4 v = *reinterpret_cast<const float4*>(E + tok * D_ + c * 256 + kf16 * 4);
        a_lds[m * 64 + (kf16 ^ (m & 7))] = v;
      }
      __syncthreads();
#pragma unroll 4
      for (int q = 0; q < 16; ++q) {
        const int kf = ks * 16 + q;
        float4 a = a_lds[lane * 64 + (kf ^ (lane & 7))];
        float4 w0 = *reinterpret_cast<const float4*>(wr + c * 256 + kf * 4);
        float4 w1 = *reinterpret_cast<const float4*>(wz + c * 256 + kf * 4);
        float4 w2 = *reinterpret_cast<const float4*>(wn + c * 256 + kf * 4);
        accR = fmaf(w0.x, a.x, accR); accR = fmaf(w0.y, a.y, accR);
        accR = fmaf(w0.z, a.z, accR); accR = fmaf(w0.w, a.w, accR);
        accZ = fmaf(w1.x, a.x, accZ); accZ = fmaf(w1.y, a.y, accZ);
        accZ = fmaf(w1.z, a.z, accZ); accZ = fmaf(w1.w, a.w, accZ);
        accIN = fmaf(w2.x, a.x, accIN); accIN = fmaf(w2.y, a.y, accIN);
        accIN = fmaf(w2.z, a.z, accIN); accIN = fmaf(w2.w, a.w, accIN);
      }
    }
  }

  // ---- cross-wave (kslice) reduction ----
  if (ks > 0) {
    float* rp = red + (((ks - 1) * 4 + jj) * 4) * 64 + lane;
    rp[0] = accR; rp[64] = accZ; rp[128] = accIN; rp[192] = accHN;
  }
  __syncthreads();
  if (ks == 0) {
#pragma unroll
    for (int t2 = 0; t2 < 3; ++t2) {
      const float* rp = red + ((t2 * 4 + jj) * 4) * 64 + lane;
      accR += rp[0]; accZ += rp[64]; accIN += rp[128]; accHN += rp[192];
    }
    float gr, gz, gin;
    if constexpr (GI) {
      gr = accR + Gi[(long long)j * 64 + lane] + b_hh[j];
      gz = accZ + Gi[(long long)(H_ + j) * 64 + lane] + b_hh[H_ + j];
      gin = accIN + Gi[(long long)(2 * H_ + j) * 64 + lane];
    } else {
      gr = accR + b_ih[j] + b_hh[j];
      gz = accZ + b_ih[H_ + j] + b_hh[H_ + j];
      gin = accIN + b_ih[2 * H_ + j];
    }
    const float ghn = accHN + b_hh[2 * H_ + j];
    const float r = 1.f / (1.f + expf(-gr));
    const float z = 1.f / (1.f + expf(-gz));
    const float n = tanhf(fmaf(r, ghn, gin));
    const long long off = (long long)lane * H_ + j;
    h_out[off] = (1.f - z) * n + z * h_in[off];
  }
}

// ---------------------------------------------------------------------------
// Logits GEMM + fused argmax. grid=500 blocks x 256 threads.
// out[b, t, n] = h[b,:] . W_out[n,:] + b_out[n]; block covers 64 n-cols.
// A (h) and W chunks (K-chunk 128) both staged in swizzled LDS.
// Argmax: per-thread best over its 16 n, LDS reduce, one atomicMax per (b)
// into keys[t*64+b] with order-encoded (value, ~index) uint64 key
// (order-independent => deterministic; first-occurrence tie-break).
// ---------------------------------------------------------------------------
__global__ __launch_bounds__(256) void k_logits2(
    const float* __restrict__ h, const float* __restrict__ W_out,
    const float* __restrict__ b_out, float* __restrict__ out,
    unsigned long long* __restrict__ keyslot, int t)
{
  __shared__ float4 a_lds[64 * 32];  // 32 KiB
  __shared__ float4 w_lds[64 * 32];  // 32 KiB
  const int tid = threadIdx.x;
  const int lane = tid & 63;
  const int wv = __builtin_amdgcn_readfirstlane(tid >> 6);
  const int bn = blockIdx.x * 64;

  float acc[16];
#pragma unroll
  for (int r = 0; r < 16; ++r) acc[r] = 0.f;

  const int akc = tid & 31;
  const int amsub = tid >> 5;
  const int wrow = tid >> 2;
  const int wfb = tid & 3;

  for (int c = 0; c < 8; ++c) {
    __syncthreads();
#pragma unroll
    for (int p = 0; p < 8; ++p) {
      const int m = p * 8 + amsub;
      float4 v = *reinterpret_cast<const float4*>(h + (long long)m * H_ + c * 128 + akc * 4);
      a_lds[m * 32 + (akc ^ (m & 7))] = v;
    }
#pragma unroll
    for (int i = 0; i < 8; ++i) {
      const int f = wfb + i * 4;
      float4 v = *reinterpret_cast<const float4*>(W_out + (long long)(bn + wrow) * H_ + c * 128 + f * 4);
      w_lds[wrow * 32 + (f ^ (wrow & 7))] = v;
    }
    __syncthreads();
    for (int kc = 0; kc < 32; ++kc) {
      float4 a = a_lds[lane * 32 + (kc ^ (lane & 7))];
#pragma unroll
      for (int r = 0; r < 16; ++r) {
        const int row = wv * 16 + r;
        float4 w = w_lds[row * 32 + (kc ^ (row & 7))];
        acc[r] = fmaf(w.x, a.x, acc[r]); acc[r] = fmaf(w.y, a.y, acc[r]);
        acc[r] = fmaf(w.z, a.z, acc[r]); acc[r] = fmaf(w.w, a.w, acc[r]);
      }
    }
  }

  // bias + store + local argmax key
  const int n0 = bn + wv * 16;
  unsigned long long best = 0ull;
  float* orow = out + (long long)lane * (T_ * (long long)V_) + (long long)t * V_ + n0;
#pragma unroll
  for (int g = 0; g < 4; ++g) {
    float vals[4];
#pragma unroll
    for (int q = 0; q < 4; ++q) vals[q] = acc[g * 4 + q] + b_out[n0 + g * 4 + q];
    float4 o; o.x = vals[0]; o.y = vals[1]; o.z = vals[2]; o.w = vals[3];
    *reinterpret_cast<float4*>(orow + g * 4) = o;
#pragma unroll
    for (int q = 0; q < 4; ++q) {
      unsigned u = __float_as_uint(vals[q]);
      u = (u & 0x80000000u) ? ~u : (u | 0x80000000u);
      const unsigned long long key =
          ((unsigned long long)u << 32) | (unsigned long long)(0xFFFFFFFFu - (unsigned)(n0 + g * 4 + q));
      if (key > best) best = key;
    }
  }
  __syncthreads();  // done reading w_lds; reuse as key-reduce buffer
  unsigned long long* sKey = reinterpret_cast<unsigned long long*>(w_lds);
  sKey[wv * 64 + lane] = best;
  __syncthreads();
  if (wv == 0) {
    unsigned long long k0 = sKey[lane];
#pragma unroll
    for (int q = 1; q < 4; ++q) {
      const unsigned long long kq = sKey[q * 64 + lane];
      if (kq > k0) k0 = kq;
    }
    atomicMax(&keyslot[lane], k0);
  }
}

// ---------------------------------------------------------------------------
// mu / logvar / z (one-shot, small)
// ---------------------------------------------------------------------------
__global__ __launch_bounds__(256) void k_mu_lv_z(
    const float* __restrict__ h, const float* __restrict__ W_mu, const float* __restrict__ b_mu,
    const float* __restrict__ W_lv, const float* __restrict__ b_lv,
    const float* __restrict__ eps, float* __restrict__ out_mu, float* __restrict__ out_lv,
    float* __restrict__ z)
{
  __shared__ float4 a_lds[64 * 64];
  const int tid = threadIdx.x;
  const int lane = tid & 63;
  const int wv = __builtin_amdgcn_readfirstlane(tid >> 6);
  const int l = blockIdx.x * 4 + wv;
  float am = 0.f, av = 0.f;
  const float* wm = W_mu + (long long)l * H_;
  const float* wl = W_lv + (long long)l * H_;
  for (int k0 = 0; k0 < H_; k0 += 256) {
    __syncthreads();
    stage_rows256(a_lds, h, H_, k0, tid);
    __syncthreads();
#pragma unroll 8
    for (int kf = 0; kf < 64; ++kf) {
      float4 a = a_lds[lane * 64 + (kf ^ (lane & 7))];
      float4 w0 = *reinterpret_cast<const float4*>(wm + k0 + kf * 4);
      float4 w1 = *reinterpret_cast<const float4*>(wl + k0 + kf * 4);
      am = fmaf(w0.x, a.x, am); am = fmaf(w0.y, a.y, am);
      am = fmaf(w0.z, a.z, am); am = fmaf(w0.w, a.w, am);
      av = fmaf(w1.x, a.x, av); av = fmaf(w1.y, a.y, av);
      av = fmaf(w1.z, a.z, av); av = fmaf(w1.w, a.w, av);
    }
  }
  const float mu = am + b_mu[l];
  const float lv = av + b_lv[l];
  const int off = lane * L_ + l;
  out_mu[off] = mu;
  out_lv[off] = lv;
  z[off] = fmaf(eps[off], expf(0.5f * lv), mu);
}

__global__ __launch_bounds__(256) void k_proj(
    const float* __restrict__ z, const float* __restrict__ W_proj,
    const float* __restrict__ b_proj, float* __restrict__ h0)
{
  __shared__ float4 a_lds[64 * 64];
  const int tid = threadIdx.x;
  const int lane = tid & 63;
  const int wv = __builtin_amdgcn_readfirstlane(tid >> 6);
  const int j = blockIdx.x * 4 + wv;
  stage_rows256(a_lds, z, L_, 0, tid);
  __syncthreads();
  float acc = 0.f;
  const float* wr = W_proj + (long long)j * L_;
#pragma unroll 8
  for (int kf = 0; kf < 64; ++kf) {
    float4 a = a_lds[lane * 64 + (kf ^ (lane & 7))];
    float4 w = *reinterpret_cast<const float4*>(wr + kf * 4);
    acc = fmaf(w.x, a.x, acc); acc = fmaf(w.y, a.y, acc);
    acc = fmaf(w.z, a.z, acc); acc = fmaf(w.w, a.w, acc);
  }
  h0[(long long)lane * H_ + j] = acc + b_proj[j];
}

// ---------------------------------------------------------------------------
extern "C" void kernel_launch(void* const* d_in, const int* in_sizes, int n_in,
                              void* d_out, int out_size, void* d_ws, size_t ws_size,
                              hipStream_t stream) {
  (void)in_sizes; (void)n_in; (void)out_size;
  const int*   x        = (const int*)d_in[0];
  const float* eps      = (const float*)d_in[1];
  const float* E        = (const float*)d_in[2];
  const float* W_ih_enc = (const float*)d_in[3];
  const float* W_hh_enc = (const float*)d_in[4];
  const float* b_ih_enc = (const float*)d_in[5];
  const float* b_hh_enc = (const float*)d_in[6];
  const float* W_mu     = (const float*)d_in[7];
  const float* b_mu     = (const float*)d_in[8];
  const float* W_lv     = (const float*)d_in[9];
  const float* b_lv     = (const float*)d_in[10];
  const float* W_proj   = (const float*)d_in[11];
  const float* b_proj   = (const float*)d_in[12];
  const float* W_ih_dec = (const float*)d_in[13];
  const float* W_hh_dec = (const float*)d_in[14];
  const float* b_ih_dec = (const float*)d_in[15];
  const float* b_hh_dec = (const float*)d_in[16];
  const float* W_out    = (const float*)d_in[17];
  const float* b_out    = (const float*)d_in[18];

  float* out = (float*)d_out;
  const long long OFF_MU = (long long)B_ * T_ * V_;
  const long long OFF_LV = OFF_MU + (long long)B_ * L_;

  float* ws = (float*)d_ws;
  float* hA = ws;                       // [64,1024]
  float* hB = ws + 65536;               // [64,1024]
  float* dA = ws + 131072;              // [64,1024]
  float* dB = ws + 196608;              // [64,1024]
  float* zb = ws + 262144;              // [64,256]
  unsigned long long* keys = (unsigned long long*)(ws + 278528);  // [64][64] keys
  float* Gi = ws + 286720;              // [64][3072][64] = 50.3 MB
  const size_t WS_MAIN = (size_t)(286720 + (long long)S_ * 3 * H_ * B_) * 4;
  const bool use_gi = (ws_size >= WS_MAIN);

  hipMemsetAsync(hA, 0, (size_t)B_ * H_ * sizeof(float), stream);
  hipMemsetAsync(keys, 0, (size_t)T_ * B_ * sizeof(unsigned long long), stream);

  // ---- encoder ----
  if (use_gi) {
    k_gates_enc<<<64 * 48, 256, 0, stream>>>(x, E, W_ih_enc, b_ih_enc, Gi);
    for (int t = 0; t < S_; ++t) {
      const float* hin = (t & 1) ? hB : hA;
      float* hout = (t & 1) ? hA : hB;
      k_gru16<0, true><<<256, 1024, 0, stream>>>(
          E, nullptr, nullptr, Gi + (long long)t * 3 * H_ * B_,
          W_ih_enc, W_hh_enc, b_ih_enc, b_hh_enc, hin, hout);
    }
  } else {
    for (int t = 0; t < S_; ++t) {
      const float* hin = (t & 1) ? hB : hA;
      float* hout = (t & 1) ? hA : hB;
      k_gru16<1, false><<<256, 1024, 0, stream>>>(
          E, x + t, nullptr, nullptr,
          W_ih_enc, W_hh_enc, b_ih_enc, b_hh_enc, hin, hout);
    }
  }
  // h_last in hA (S_=64 even)

  // ---- latent ----
  k_mu_lv_z<<<64, 256, 0, stream>>>(hA, W_mu, b_mu, W_lv, b_lv, eps,
                                    out + OFF_MU, out + OFF_LV, zb);
  k_proj<<<256, 256, 0, stream>>>(zb, W_proj, b_proj, dA);

  // ---- decoder ----
  for (int t = 0; t < T_; ++t) {
    const float* hin = (t & 1) ? dB : dA;
    float* hout = (t & 1) ? dA : dB;
    if (t == 0) {
      k_gru16<0, false><<<256, 1024, 0, stream>>>(
          E, nullptr, nullptr, nullptr,
          W_ih_dec, W_hh_dec, b_ih_dec, b_hh_dec, hin, hout);
    } else {
      k_gru16<2, false><<<256, 1024, 0, stream>>>(
          E, nullptr, keys + (long long)(t - 1) * B_, nullptr,
          W_ih_dec, W_hh_dec, b_ih_dec, b_hh_dec, hin, hout);
    }
    k_logits2<<<500, 256, 0, stream>>>(hout, W_out, b_out, out, keys + (long long)t * B_, t);
  }
}

// Round 3
// 6068.235 us; speedup vs baseline: 4.3396x; 1.7367x over previous
//
#include <hip/hip_runtime.h>

// Problem constants
#define B_ 64
#define S_ 64
#define T_ 64
#define V_ 32000
#define D_ 512
#define H_ 1024
#define L_ 256

typedef _Float16 f16;
typedef __attribute__((ext_vector_type(4))) _Float16 f16x4;
typedef __attribute__((ext_vector_type(8))) _Float16 f16x8;
typedef __attribute__((ext_vector_type(16))) float f32x16;

// ---------------------------------------------------------------------------
// LDS staging helper (256-thread blocks): 64 rows x 256 floats, swizzled.
// ---------------------------------------------------------------------------
__device__ __forceinline__ void stage_rows256(float4* a_lds, const float* __restrict__ A,
                                              int rowStride, int k0, int tid) {
  const int kf = tid & 63;
  const int msub = tid >> 6;
#pragma unroll
  for (int p = 0; p < 16; ++p) {
    const int m = p * 4 + msub;
    float4 v = *reinterpret_cast<const float4*>(A + (long long)m * rowStride + k0 + kf * 4);
    a_lds[m * 64 + (kf ^ (m & 7))] = v;
  }
}

// ---------------------------------------------------------------------------
// One-time pack of W_out (fp32 [32000][1024]) into MFMA B-fragment-major
// f16 hi/lo arrays. Frag layout for v_mfma_f32_32x32x16_f16 B-operand:
// n = nt*32 + (lane&31), k = ks*16 + (lane>>5)*8 + e.
// Array: B16[nt][ks][lane][e]  (e contiguous, 8 f16 = 16B per lane).
// lo is scaled by 2048 to stay in f16 normal range; combined later as /2048.
// ---------------------------------------------------------------------------
__global__ __launch_bounds__(256) void k_pack_w(
    const float* __restrict__ W, f16* __restrict__ Bhi, f16* __restrict__ Blo)
{
  const int n = blockIdx.x;
  const int k = threadIdx.x * 4;
  float4 w = *reinterpret_cast<const float4*>(W + (long long)n * H_ + k);
  float wv[4] = {w.x, w.y, w.z, w.w};
  f16x4 hi, lo;
#pragma unroll
  for (int i = 0; i < 4; ++i) {
    const f16 h = (f16)wv[i];
    hi[i] = h;
    lo[i] = (f16)((wv[i] - (float)h) * 2048.0f);
  }
  const int nt = n >> 5;
  const int lane = (n & 31) + 32 * ((k >> 3) & 1);
  const int ks = k >> 4;
  const long long off = (((long long)nt * 64 + ks) * 64 + lane) * 8 + (k & 7);
  *reinterpret_cast<f16x4*>(Bhi + off) = hi;
  *reinterpret_cast<f16x4*>(Blo + off) = lo;
}

// ---------------------------------------------------------------------------
// Encoder input-gates GEMM (unchanged from round 2).
// ---------------------------------------------------------------------------
__global__ __launch_bounds__(256) void k_gates_enc(
    const int* __restrict__ x, const float* __restrict__ E,
    const float* __restrict__ W_ih, const float* __restrict__ b_ih,
    float* __restrict__ Gi)
{
  __shared__ float4 a_lds[64 * 32];
  __shared__ float4 w_lds[64 * 32];
  const int tid = threadIdx.x;
  const int lane = tid & 63;
  const int wv = __builtin_amdgcn_readfirstlane(tid >> 6);
  const int s = blockIdx.x / 48;
  const int bn = (blockIdx.x % 48) * 64;

  float acc[16];
#pragma unroll
  for (int r = 0; r < 16; ++r) acc[r] = 0.f;

  const int akc = tid & 31;
  const int amsub = tid >> 5;
  const int wrow = tid >> 2;
  const int wfb = tid & 3;

  for (int c = 0; c < 4; ++c) {
    __syncthreads();
#pragma unroll
    for (int p = 0; p < 8; ++p) {
      const int m = p * 8 + amsub;
      const long long tok = x[m * S_ + s];
      float4 v = *reinterpret_cast<const float4*>(E + tok * D_ + c * 128 + akc * 4);
      a_lds[m * 32 + (akc ^ (m & 7))] = v;
    }
#pragma unroll
    for (int i = 0; i < 8; ++i) {
      const int f = wfb + i * 4;
      float4 v = *reinterpret_cast<const float4*>(W_ih + (long long)(bn + wrow) * D_ + c * 128 + f * 4);
      w_lds[wrow * 32 + (f ^ (wrow & 7))] = v;
    }
    __syncthreads();
    for (int kc = 0; kc < 32; ++kc) {
      float4 a = a_lds[lane * 32 + (kc ^ (lane & 7))];
#pragma unroll
      for (int r = 0; r < 16; ++r) {
        const int row = wv * 16 + r;
        float4 w = w_lds[row * 32 + (kc ^ (row & 7))];
        acc[r] = fmaf(w.x, a.x, acc[r]); acc[r] = fmaf(w.y, a.y, acc[r]);
        acc[r] = fmaf(w.z, a.z, acc[r]); acc[r] = fmaf(w.w, a.w, acc[r]);
      }
    }
  }
  const int n0 = bn + wv * 16;
#pragma unroll
  for (int r = 0; r < 16; ++r) {
    const int n = n0 + r;
    Gi[((long long)s * (3 * H_) + n) * 64 + lane] = acc[r] + b_ih[n];
  }
}

// ---------------------------------------------------------------------------
// GRU step, 16-wave. XMODE: 0 = no x; 1 = tokens from int array (enc
// fallback); 2 = tokens from bestPart partial-argmax fold (new decoder);
// 3 = tokens from per-step keys (old decoder fallback).
// GI: add precomputed input gates. PACK: write h_out also as f16 hi/lo
// A-fragments for the logits MFMA kernel.
// ---------------------------------------------------------------------------
template <int XMODE, bool GI, bool PACK>
__global__ __launch_bounds__(1024) void k_gru16(
    const float* __restrict__ E, const int* __restrict__ toki,
    const unsigned long long* __restrict__ keys, const float* __restrict__ Gi,
    const float* __restrict__ W_ih, const float* __restrict__ W_hh,
    const float* __restrict__ b_ih, const float* __restrict__ b_hh,
    const float* __restrict__ h_in, float* __restrict__ h_out,
    f16* __restrict__ Ahi, f16* __restrict__ Alo)
{
  __shared__ float4 a_lds[64 * 64];     // 64 KiB staging
  __shared__ float red[3 * 4 * 4 * 64]; // 12 KiB cross-wave reduction
  __shared__ int toks[64];
  const int tid = threadIdx.x;
  const int lane = tid & 63;
  const int wv = __builtin_amdgcn_readfirstlane(tid >> 6);
  const int jj = wv & 3;
  const int ks = wv >> 2;
  const int j = blockIdx.x * 4 + jj;

  const int kf16 = tid & 63;
  const int msub = tid >> 6;

  // ---- fold partial argmax (250 blocks) into per-row token, once ----
  if constexpr (XMODE == 2) {
#pragma unroll
    for (int rr = 0; rr < 4; ++rr) {
      const int r = wv + rr * 16;
      unsigned long long kk = 0ull;
      for (int i = lane; i < 250; i += 64) {
        const unsigned long long q = keys[(long long)r * 256 + i];
        if (q > kk) kk = q;
      }
#pragma unroll
      for (int m = 1; m < 64; m <<= 1) {
        const unsigned long long q = __shfl_xor(kk, m, 64);
        if (q > kk) kk = q;
      }
      if (lane == 0) toks[r] = (int)(0xFFFFFFFFu - (unsigned)(kk & 0xFFFFFFFFull));
    }
    __syncthreads();
  }

  float accR = 0.f, accZ = 0.f, accIN = 0.f, accHN = 0.f;

  // ---- hidden part: K = 1024, 4 chunks of 256 ----
  {
    const float* wr = W_hh + (long long)j * H_;
    const float* wz = W_hh + (long long)(j + H_) * H_;
    const float* wn = W_hh + (long long)(j + 2 * H_) * H_;
    for (int c = 0; c < 4; ++c) {
      __syncthreads();
#pragma unroll
      for (int p = 0; p < 4; ++p) {
        const int m = p * 16 + msub;
        float4 v = *reinterpret_cast<const float4*>(h_in + (long long)m * H_ + c * 256 + kf16 * 4);
        a_lds[m * 64 + (kf16 ^ (m & 7))] = v;
      }
      __syncthreads();
#pragma unroll 4
      for (int q = 0; q < 16; ++q) {
        const int kf = ks * 16 + q;
        float4 a = a_lds[lane * 64 + (kf ^ (lane & 7))];
        float4 w0 = *reinterpret_cast<const float4*>(wr + c * 256 + kf * 4);
        float4 w1 = *reinterpret_cast<const float4*>(wz + c * 256 + kf * 4);
        float4 w2 = *reinterpret_cast<const float4*>(wn + c * 256 + kf * 4);
        accR = fmaf(w0.x, a.x, accR); accR = fmaf(w0.y, a.y, accR);
        accR = fmaf(w0.z, a.z, accR); accR = fmaf(w0.w, a.w, accR);
        accZ = fmaf(w1.x, a.x, accZ); accZ = fmaf(w1.y, a.y, accZ);
        accZ = fmaf(w1.z, a.z, accZ); accZ = fmaf(w1.w, a.w, accZ);
        accHN = fmaf(w2.x, a.x, accHN); accHN = fmaf(w2.y, a.y, accHN);
        accHN = fmaf(w2.z, a.z, accHN); accHN = fmaf(w2.w, a.w, accHN);
      }
    }
  }

  // ---- input part: K = 512, 2 chunks of 256 (gathered embeddings) ----
  if constexpr (XMODE != 0) {
    const float* wr = W_ih + (long long)j * D_;
    const float* wz = W_ih + (long long)(j + H_) * D_;
    const float* wn = W_ih + (long long)(j + 2 * H_) * D_;
    for (int c = 0; c < 2; ++c) {
      __syncthreads();
#pragma unroll
      for (int p = 0; p < 4; ++p) {
        const int m = p * 16 + msub;
        long long tok;
        if constexpr (XMODE == 1) tok = toki[m * S_];
        else if constexpr (XMODE == 2) tok = toks[m];
        else tok = (long long)(0xFFFFFFFFu - (unsigned)(keys[m] & 0xFFFFFFFFull));
        float4 v = *reinterpret_cast<const float4*>(E + tok * D_ + c * 256 + kf16 * 4);
        a_lds[m * 64 + (kf16 ^ (m & 7))] = v;
      }
      __syncthreads();
#pragma unroll 4
      for (int q = 0; q < 16; ++q) {
        const int kf = ks * 16 + q;
        float4 a = a_lds[lane * 64 + (kf ^ (lane & 7))];
        float4 w0 = *reinterpret_cast<const float4*>(wr + c * 256 + kf * 4);
        float4 w1 = *reinterpret_cast<const float4*>(wz + c * 256 + kf * 4);
        float4 w2 = *reinterpret_cast<const float4*>(wn + c * 256 + kf * 4);
        accR = fmaf(w0.x, a.x, accR); accR = fmaf(w0.y, a.y, accR);
        accR = fmaf(w0.z, a.z, accR); accR = fmaf(w0.w, a.w, accR);
        accZ = fmaf(w1.x, a.x, accZ); accZ = fmaf(w1.y, a.y, accZ);
        accZ = fmaf(w1.z, a.z, accZ); accZ = fmaf(w1.w, a.w, accZ);
        accIN = fmaf(w2.x, a.x, accIN); accIN = fmaf(w2.y, a.y, accIN);
        accIN = fmaf(w2.z, a.z, accIN); accIN = fmaf(w2.w, a.w, accIN);
      }
    }
  }

  // ---- cross-wave (kslice) reduction ----
  if (ks > 0) {
    float* rp = red + (((ks - 1) * 4 + jj) * 4) * 64 + lane;
    rp[0] = accR; rp[64] = accZ; rp[128] = accIN; rp[192] = accHN;
  }
  __syncthreads();
  if (ks == 0) {
#pragma unroll
    for (int t2 = 0; t2 < 3; ++t2) {
      const float* rp = red + ((t2 * 4 + jj) * 4) * 64 + lane;
      accR += rp[0]; accZ += rp[64]; accIN += rp[128]; accHN += rp[192];
    }
    float gr, gz, gin;
    if constexpr (GI) {
      gr = accR + Gi[(long long)j * 64 + lane] + b_hh[j];
      gz = accZ + Gi[(long long)(H_ + j) * 64 + lane] + b_hh[H_ + j];
      gin = accIN + Gi[(long long)(2 * H_ + j) * 64 + lane];
    } else {
      gr = accR + b_ih[j] + b_hh[j];
      gz = accZ + b_ih[H_ + j] + b_hh[H_ + j];
      gin = accIN + b_ih[2 * H_ + j];
    }
    const float ghn = accHN + b_hh[2 * H_ + j];
    const float r = 1.f / (1.f + expf(-gr));
    const float z = 1.f / (1.f + expf(-gz));
    const float n = tanhf(fmaf(r, ghn, gin));
    const long long off = (long long)lane * H_ + j;
    const float hv = (1.f - z) * n + z * h_in[off];
    h_out[off] = hv;
    if constexpr (PACK) {
      // A-fragment layout: m = lane (batch), k = j.
      const f16 hi = (f16)hv;
      const f16 lo = (f16)((hv - (float)hi) * 2048.0f);
      const int mt = lane >> 5, mm = lane & 31;
      const int ks2 = j >> 4, kh = (j >> 3) & 1, e = j & 7;
      const long long fo = (((long long)mt * 64 + ks2) * 64 + (mm + 32 * kh)) * 8 + e;
      Ahi[fo] = hi; Alo[fo] = lo;
    }
  }
}

// ---------------------------------------------------------------------------
// MFMA f16x3 logits GEMM + fused partial argmax. grid=250 x 256 threads.
// Wave wv owns n-tile nt = blockIdx*4+wv (32 vocab cols), computes 2 m-tiles
// (64 batch rows). All operands stream from global (L2/L3-resident frag
// arrays); no LDS in the GEMM loop. logits = accM + accL/2048 + b_out.
// Partial argmax keys written to bestPart[row][blockIdx] (no atomics).
// ---------------------------------------------------------------------------
__global__ __launch_bounds__(256) void k_logits3(
    const f16* __restrict__ Ahi, const f16* __restrict__ Alo,
    const f16* __restrict__ Bhi, const f16* __restrict__ Blo,
    const float* __restrict__ b_out, float* __restrict__ out,
    unsigned long long* __restrict__ bestPart, int t)
{
  __shared__ float cand[4][64][32];           // 32 KiB
  __shared__ unsigned long long wbest[4][64]; // 2 KiB
  const int tid = threadIdx.x;
  const int lane = tid & 63;
  const int wv = __builtin_amdgcn_readfirstlane(tid >> 6);
  const int nt = blockIdx.x * 4 + wv;

  f32x16 accM0, accM1, accL0, accL1;
#pragma unroll
  for (int i = 0; i < 16; ++i) { accM0[i] = 0.f; accM1[i] = 0.f; accL0[i] = 0.f; accL1[i] = 0.f; }

  const f16x8* pAh0 = reinterpret_cast<const f16x8*>(Ahi) + lane;
  const f16x8* pAh1 = reinterpret_cast<const f16x8*>(Ahi) + 4096 + lane;
  const f16x8* pAl0 = reinterpret_cast<const f16x8*>(Alo) + lane;
  const f16x8* pAl1 = reinterpret_cast<const f16x8*>(Alo) + 4096 + lane;
  const f16x8* pBh = reinterpret_cast<const f16x8*>(Bhi) + (long long)nt * 4096 + lane;
  const f16x8* pBl = reinterpret_cast<const f16x8*>(Blo) + (long long)nt * 4096 + lane;

#pragma unroll 4
  for (int ks = 0; ks < 64; ++ks) {
    const int o = ks * 64;
    f16x8 bh = pBh[o];
    f16x8 bl = pBl[o];
    f16x8 ah0 = pAh0[o];
    f16x8 ah1 = pAh1[o];
    f16x8 al0 = pAl0[o];
    f16x8 al1 = pAl1[o];
    accM0 = __builtin_amdgcn_mfma_f32_32x32x16_f16(ah0, bh, accM0, 0, 0, 0);
    accM1 = __builtin_amdgcn_mfma_f32_32x32x16_f16(ah1, bh, accM1, 0, 0, 0);
    accL0 = __builtin_amdgcn_mfma_f32_32x32x16_f16(ah0, bl, accL0, 0, 0, 0);
    accL1 = __builtin_amdgcn_mfma_f32_32x32x16_f16(ah1, bl, accL1, 0, 0, 0);
    accL0 = __builtin_amdgcn_mfma_f32_32x32x16_f16(al0, bh, accL0, 0, 0, 0);
    accL1 = __builtin_amdgcn_mfma_f32_32x32x16_f16(al1, bh, accL1, 0, 0, 0);
  }

  const int nn = nt * 32 + (lane & 31);
  const float bo = b_out[nn];
  const int rbase = 4 * (lane >> 5);
  const float invS = 1.0f / 2048.0f;
#pragma unroll
  for (int reg = 0; reg < 16; ++reg) {
    const int row0 = (reg & 3) + 8 * (reg >> 2) + rbase;
    const float v0 = accM0[reg] + accL0[reg] * invS + bo;
    out[(long long)row0 * (T_ * (long long)V_) + (long long)t * V_ + nn] = v0;
    cand[wv][row0][lane & 31] = v0;
    const int row1 = row0 + 32;
    const float v1 = accM1[reg] + accL1[reg] * invS + bo;
    out[(long long)row1 * (T_ * (long long)V_) + (long long)t * V_ + nn] = v1;
    cand[wv][row1][lane & 31] = v1;
  }
  __syncthreads();
  {
    const int w = tid >> 6, r = tid & 63;
    const int nb = (blockIdx.x * 4 + w) * 32;
    unsigned long long kk = 0ull;
#pragma unroll
    for (int l0 = 0; l0 < 32; ++l0) {
      const int l = (l0 + r) & 31;  // rotation avoids LDS bank conflicts
      const float v = cand[w][r][l];
      unsigned u = __float_as_uint(v);
      u = (u & 0x80000000u) ? ~u : (u | 0x80000000u);
      const unsigned long long key = ((unsigned long long)u << 32) |
          (unsigned long long)(0xFFFFFFFFu - (unsigned)(nb + l));
      if (key > kk) kk = key;
    }
    wbest[w][r] = kk;
  }
  __syncthreads();
  if (tid < 64) {
    unsigned long long kk = wbest[0][tid];
#pragma unroll
    for (int w = 1; w < 4; ++w) { const unsigned long long q = wbest[w][tid]; if (q > kk) kk = q; }
    bestPart[(long long)tid * 256 + blockIdx.x] = kk;
  }
}

// ---------------------------------------------------------------------------
// Fallback fp32 logits (round-2 path, used only if ws is too small).
// ---------------------------------------------------------------------------
__global__ __launch_bounds__(256) void k_logits2(
    const float* __restrict__ h, const float* __restrict__ W_out,
    const float* __restrict__ b_out, float* __restrict__ out,
    unsigned long long* __restrict__ keyslot, int t)
{
  __shared__ float4 a_lds[64 * 32];
  __shared__ float4 w_lds[64 * 32];
  const int tid = threadIdx.x;
  const int lane = tid & 63;
  const int wv = __builtin_amdgcn_readfirstlane(tid >> 6);
  const int bn = blockIdx.x * 64;

  float acc[16];
#pragma unroll
  for (int r = 0; r < 16; ++r) acc[r] = 0.f;

  const int akc = tid & 31;
  const int amsub = tid >> 5;
  const int wrow = tid >> 2;
  const int wfb = tid & 3;

  for (int c = 0; c < 8; ++c) {
    __syncthreads();
#pragma unroll
    for (int p = 0; p < 8; ++p) {
      const int m = p * 8 + amsub;
      float4 v = *reinterpret_cast<const float4*>(h + (long long)m * H_ + c * 128 + akc * 4);
      a_lds[m * 32 + (akc ^ (m & 7))] = v;
    }
#pragma unroll
    for (int i = 0; i < 8; ++i) {
      const int f = wfb + i * 4;
      float4 v = *reinterpret_cast<const float4*>(W_out + (long long)(bn + wrow) * H_ + c * 128 + f * 4);
      w_lds[wrow * 32 + (f ^ (wrow & 7))] = v;
    }
    __syncthreads();
    for (int kc = 0; kc < 32; ++kc) {
      float4 a = a_lds[lane * 32 + (kc ^ (lane & 7))];
#pragma unroll
      for (int r = 0; r < 16; ++r) {
        const int row = wv * 16 + r;
        float4 w = w_lds[row * 32 + (kc ^ (row & 7))];
        acc[r] = fmaf(w.x, a.x, acc[r]); acc[r] = fmaf(w.y, a.y, acc[r]);
        acc[r] = fmaf(w.z, a.z, acc[r]); acc[r] = fmaf(w.w, a.w, acc[r]);
      }
    }
  }

  const int n0 = bn + wv * 16;
  unsigned long long best = 0ull;
  float* orow = out + (long long)lane * (T_ * (long long)V_) + (long long)t * V_ + n0;
#pragma unroll
  for (int g = 0; g < 4; ++g) {
    float vals[4];
#pragma unroll
    for (int q = 0; q < 4; ++q) vals[q] = acc[g * 4 + q] + b_out[n0 + g * 4 + q];
    float4 o; o.x = vals[0]; o.y = vals[1]; o.z = vals[2]; o.w = vals[3];
    *reinterpret_cast<float4*>(orow + g * 4) = o;
#pragma unroll
    for (int q = 0; q < 4; ++q) {
      unsigned u = __float_as_uint(vals[q]);
      u = (u & 0x80000000u) ? ~u : (u | 0x80000000u);
      const unsigned long long key =
          ((unsigned long long)u << 32) | (unsigned long long)(0xFFFFFFFFu - (unsigned)(n0 + g * 4 + q));
      if (key > best) best = key;
    }
  }
  __syncthreads();
  unsigned long long* sKey = reinterpret_cast<unsigned long long*>(w_lds);
  sKey[wv * 64 + lane] = best;
  __syncthreads();
  if (wv == 0) {
    unsigned long long k0 = sKey[lane];
#pragma unroll
    for (int q = 1; q < 4; ++q) {
      const unsigned long long kq = sKey[q * 64 + lane];
      if (kq > k0) k0 = kq;
    }
    atomicMax(&keyslot[lane], k0);
  }
}

// ---------------------------------------------------------------------------
// mu / logvar / z and proj (small one-shots, unchanged)
// ---------------------------------------------------------------------------
__global__ __launch_bounds__(256) void k_mu_lv_z(
    const float* __restrict__ h, const float* __restrict__ W_mu, const float* __restrict__ b_mu,
    const float* __restrict__ W_lv, const float* __restrict__ b_lv,
    const float* __restrict__ eps, float* __restrict__ out_mu, float* __restrict__ out_lv,
    float* __restrict__ z)
{
  __shared__ float4 a_lds[64 * 64];
  const int tid = threadIdx.x;
  const int lane = tid & 63;
  const int wv = __builtin_amdgcn_readfirstlane(tid >> 6);
  const int l = blockIdx.x * 4 + wv;
  float am = 0.f, av = 0.f;
  const float* wm = W_mu + (long long)l * H_;
  const float* wl = W_lv + (long long)l * H_;
  for (int k0 = 0; k0 < H_; k0 += 256) {
    __syncthreads();
    stage_rows256(a_lds, h, H_, k0, tid);
    __syncthreads();
#pragma unroll 8
    for (int kf = 0; kf < 64; ++kf) {
      float4 a = a_lds[lane * 64 + (kf ^ (lane & 7))];
      float4 w0 = *reinterpret_cast<const float4*>(wm + k0 + kf * 4);
      float4 w1 = *reinterpret_cast<const float4*>(wl + k0 + kf * 4);
      am = fmaf(w0.x, a.x, am); am = fmaf(w0.y, a.y, am);
      am = fmaf(w0.z, a.z, am); am = fmaf(w0.w, a.w, am);
      av = fmaf(w1.x, a.x, av); av = fmaf(w1.y, a.y, av);
      av = fmaf(w1.z, a.z, av); av = fmaf(w1.w, a.w, av);
    }
  }
  const float mu = am + b_mu[l];
  const float lv = av + b_lv[l];
  const int off = lane * L_ + l;
  out_mu[off] = mu;
  out_lv[off] = lv;
  z[off] = fmaf(eps[off], expf(0.5f * lv), mu);
}

__global__ __launch_bounds__(256) void k_proj(
    const float* __restrict__ z, const float* __restrict__ W_proj,
    const float* __restrict__ b_proj, float* __restrict__ h0)
{
  __shared__ float4 a_lds[64 * 64];
  const int tid = threadIdx.x;
  const int lane = tid & 63;
  const int wv = __builtin_amdgcn_readfirstlane(tid >> 6);
  const int j = blockIdx.x * 4 + wv;
  stage_rows256(a_lds, z, L_, 0, tid);
  __syncthreads();
  float acc = 0.f;
  const float* wr = W_proj + (long long)j * L_;
#pragma unroll 8
  for (int kf = 0; kf < 64; ++kf) {
    float4 a = a_lds[lane * 64 + (kf ^ (lane & 7))];
    float4 w = *reinterpret_cast<const float4*>(wr + kf * 4);
    acc = fmaf(w.x, a.x, acc); acc = fmaf(w.y, a.y, acc);
    acc = fmaf(w.z, a.z, acc); acc = fmaf(w.w, a.w, acc);
  }
  h0[(long long)lane * H_ + j] = acc + b_proj[j];
}

// ---------------------------------------------------------------------------
extern "C" void kernel_launch(void* const* d_in, const int* in_sizes, int n_in,
                              void* d_out, int out_size, void* d_ws, size_t ws_size,
                              hipStream_t stream) {
  (void)in_sizes; (void)n_in; (void)out_size;
  const int*   x        = (const int*)d_in[0];
  const float* eps      = (const float*)d_in[1];
  const float* E        = (const float*)d_in[2];
  const float* W_ih_enc = (const float*)d_in[3];
  const float* W_hh_enc = (const float*)d_in[4];
  const float* b_ih_enc = (const float*)d_in[5];
  const float* b_hh_enc = (const float*)d_in[6];
  const float* W_mu     = (const float*)d_in[7];
  const float* b_mu     = (const float*)d_in[8];
  const float* W_lv     = (const float*)d_in[9];
  const float* b_lv     = (const float*)d_in[10];
  const float* W_proj   = (const float*)d_in[11];
  const float* b_proj   = (const float*)d_in[12];
  const float* W_ih_dec = (const float*)d_in[13];
  const float* W_hh_dec = (const float*)d_in[14];
  const float* b_ih_dec = (const float*)d_in[15];
  const float* b_hh_dec = (const float*)d_in[16];
  const float* W_out    = (const float*)d_in[17];
  const float* b_out    = (const float*)d_in[18];

  float* out = (float*)d_out;
  const long long OFF_MU = (long long)B_ * T_ * V_;
  const long long OFF_LV = OFF_MU + (long long)B_ * L_;

  float* ws = (float*)d_ws;
  float* hA = ws;                        // [64,1024]
  float* hB = ws + 65536;
  float* dA = ws + 131072;
  float* dB = ws + 196608;
  float* zb = ws + 262144;               // [64,256]
  unsigned long long* bestPart = (unsigned long long*)(ws + 278528);  // [64][256] u64
  float* Gi  = ws + 311296;              // [64][3072][64]
  f16*   Ahi = (f16*)(ws + 12894208);    // [2][64][64][8] f16
  f16*   Alo = (f16*)(ws + 12926976);
  f16*   Bhi = (f16*)(ws + 12959744);    // [1000][64][64][8] f16
  f16*   Blo = (f16*)(ws + 29343744);
  const size_t WS_FULL = (size_t)45727744 * 4;
  const size_t WS_GI   = (size_t)12894208 * 4;

  hipMemsetAsync(hA, 0, (size_t)B_ * H_ * sizeof(float), stream);

  if (ws_size >= WS_FULL) {
    // ======== MFMA-logits path ========
    hipMemsetAsync(bestPart, 0, (size_t)64 * 256 * 8, stream);
    k_pack_w<<<V_, 256, 0, stream>>>(W_out, Bhi, Blo);

    k_gates_enc<<<64 * 48, 256, 0, stream>>>(x, E, W_ih_enc, b_ih_enc, Gi);
    for (int t = 0; t < S_; ++t) {
      const float* hin = (t & 1) ? hB : hA;
      float* hout = (t & 1) ? hA : hB;
      k_gru16<0, true, false><<<256, 1024, 0, stream>>>(
          E, nullptr, nullptr, Gi + (long long)t * 3 * H_ * B_,
          W_ih_enc, W_hh_enc, b_ih_enc, b_hh_enc, hin, hout, nullptr, nullptr);
    }
    k_mu_lv_z<<<64, 256, 0, stream>>>(hA, W_mu, b_mu, W_lv, b_lv, eps,
                                      out + OFF_MU, out + OFF_LV, zb);
    k_proj<<<256, 256, 0, stream>>>(zb, W_proj, b_proj, dA);

    for (int t = 0; t < T_; ++t) {
      const float* hin = (t & 1) ? dB : dA;
      float* hout = (t & 1) ? dA : dB;
      if (t == 0) {
        k_gru16<0, false, true><<<256, 1024, 0, stream>>>(
            E, nullptr, nullptr, nullptr,
            W_ih_dec, W_hh_dec, b_ih_dec, b_hh_dec, hin, hout, Ahi, Alo);
      } else {
        k_gru16<2, false, true><<<256, 1024, 0, stream>>>(
            E, nullptr, bestPart, nullptr,
            W_ih_dec, W_hh_dec, b_ih_dec, b_hh_dec, hin, hout, Ahi, Alo);
      }
      k_logits3<<<250, 256, 0, stream>>>(Ahi, Alo, Bhi, Blo, b_out, out, bestPart, t);
    }
  } else {
    // ======== fallback: round-2 fp32 path ========
    unsigned long long* keys = bestPart;  // [64][64] per-step keys
    hipMemsetAsync(keys, 0, (size_t)T_ * B_ * sizeof(unsigned long long), stream);
    const bool use_gi = (ws_size >= WS_GI);
    if (use_gi) {
      k_gates_enc<<<64 * 48, 256, 0, stream>>>(x, E, W_ih_enc, b_ih_enc, Gi);
      for (int t = 0; t < S_; ++t) {
        const float* hin = (t & 1) ? hB : hA;
        float* hout = (t & 1) ? hA : hB;
        k_gru16<0, true, false><<<256, 1024, 0, stream>>>(
            E, nullptr, nullptr, Gi + (long long)t * 3 * H_ * B_,
            W_ih_enc, W_hh_enc, b_ih_enc, b_hh_enc, hin, hout, nullptr, nullptr);
      }
    } else {
      for (int t = 0; t < S_; ++t) {
        const float* hin = (t & 1) ? hB : hA;
        float* hout = (t & 1) ? hA : hB;
        k_gru16<1, false, false><<<256, 1024, 0, stream>>>(
            E, x + t, nullptr, nullptr,
            W_ih_enc, W_hh_enc, b_ih_enc, b_hh_enc, hin, hout, nullptr, nullptr);
      }
    }
    k_mu_lv_z<<<64, 256, 0, stream>>>(hA, W_mu, b_mu, W_lv, b_lv, eps,
                                      out + OFF_MU, out + OFF_LV, zb);
    k_proj<<<256, 256, 0, stream>>>(zb, W_proj, b_proj, dA);
    for (int t = 0; t < T_; ++t) {
      const float* hin = (t & 1) ? dB : dA;
      float* hout = (t & 1) ? dA : dB;
      if (t == 0) {
        k_gru16<0, false, false><<<256, 1024, 0, stream>>>(
            E, nullptr, nullptr, nullptr,
            W_ih_dec, W_hh_dec, b_ih_dec, b_hh_dec, hin, hout, nullptr, nullptr);
      } else {
        k_gru16<3, false, false><<<256, 1024, 0, stream>>>(
            E, nullptr, keys + (long long)(t - 1) * B_, nullptr,
            W_ih_dec, W_hh_dec, b_ih_dec, b_hh_dec, hin, hout, nullptr, nullptr);
      }
      k_logits2<<<500, 256, 0, stream>>>(hout, W_out, b_out, out, keys + (long long)t * B_, t);
    }
  }
}